// Round 7
// baseline (25216.100 us; speedup 1.0000x reference)
//
#include <hip/hip_runtime.h>
#include <math.h>

// ---------------- problem constants ----------------
constexpr int MM = 8;      // batch of GPs
constexpr int NC = 1024;   // context points
constexpr int NT = 512;    // target points

// Workspace (floats):
//  Kb   : MM*1024*1024   (K raw/Schur; G = K^-1 written only at final step)
//  Ab   : MM*1024*1024   (diag-block inverses + L panels -> A = L^-1)
//  Tb   : MM*512*512     (trinv temp; v at alpha; S1/S2 at predict)
//  Ktc  : MM*NT*NC
//  alpha: MM*1024
//  scal : MM*32  ([0..3] raw, [4..7] adam m, [8..11] adam v, [12]ls [13]os [14]noi [15]cm)
//  acc  : MM*8   ([T1, T2, trG] per m)
//  ctr  : MM u32 (syrk completion tickets)
constexpr size_t OFF_A     = (size_t)MM * 1024 * 1024;
constexpr size_t OFF_T     = OFF_A * 2;
constexpr size_t OFF_KTC   = OFF_T + (size_t)MM * 512 * 512;
constexpr size_t OFF_ALPHA = OFF_KTC + (size_t)MM * NT * NC;
constexpr size_t OFF_SCAL  = OFF_ALPHA + (size_t)MM * 1024;
constexpr size_t OFF_ACC   = OFF_SCAL + (size_t)MM * 32;
constexpr size_t OFF_CTR   = OFF_ACC + (size_t)MM * 8;

#define S5 2.2360679775f

__device__ __forceinline__ float sigmf(float x) { return 1.0f / (1.0f + expf(-x)); }
__device__ __forceinline__ float softplusf(float x) { return fmaxf(x, 0.0f) + log1pf(expf(-fabsf(x))); }

__device__ __forceinline__ void lt_decode(int x, int& i, int& j) {
  int ii = 0;
  while ((ii + 1) * (ii + 2) / 2 <= x) ++ii;
  i = ii; j = x - ii * (ii + 1) / 2;
}

// Shared mem for 64-tile kernels (~47.5 KB)
struct SMem {
  float Ls[64 * 65];
  float Us[64 * 65];
  float Tt[32 * 33];
  float dvec[64];
  float As[16][68];
  float Bs[16][68];
  float xi[64][3];
  float xj[64][3];
  float ai[64];
  float aj[64];
  float red[4][4];
};

// Shared mem for 128-tile GEMM kernels (~21 KB -> 3 blocks/CU)
struct SMem128 {
  float As[16][132];
  float Bs[16][132];
  float xi[128][3];
  float xj[128][3];
  float ai[128];
  float aj[128];
  float red[4][4];
};

// ---------------- 64-tile GEMM (4x4 micro, register prefetch) ----------------
template <int TA, int TB>
__device__ __forceinline__ void gemm64(const float* __restrict__ A, int lda,
                                       const float* __restrict__ B, int ldb,
                                       int kBeg, int kEnd, float acc[4][4], SMem& sm) {
  int tid = threadIdx.x, tx = tid & 15, ty = tid >> 4;
  float ra[4], rb[4];
  auto ldAB = [&](int k0) {
#pragma unroll
    for (int q = 0; q < 4; ++q) {
      int e = tid + (q << 8);
      if (TA) { int kk = e >> 6, r = e & 63; ra[q] = A[(size_t)(k0 + kk) * lda + r]; }
      else    { int r = e >> 4, kk = e & 15; ra[q] = A[(size_t)r * lda + k0 + kk]; }
      if (TB) { int c = e >> 4, kk = e & 15; rb[q] = B[(size_t)c * ldb + k0 + kk]; }
      else    { int kk = e >> 6, c = e & 63; rb[q] = B[(size_t)(k0 + kk) * ldb + c]; }
    }
  };
  ldAB(kBeg);
  for (int k0 = kBeg; k0 < kEnd; k0 += 16) {
    __syncthreads();
#pragma unroll
    for (int q = 0; q < 4; ++q) {
      int e = tid + (q << 8);
      if (TA) sm.As[e >> 6][e & 63] = ra[q]; else sm.As[e & 15][e >> 4] = ra[q];
      if (TB) sm.Bs[e & 15][e >> 4] = rb[q]; else sm.Bs[e >> 6][e & 63] = rb[q];
    }
    __syncthreads();
    if (k0 + 16 < kEnd) ldAB(k0 + 16);
#pragma unroll
    for (int kk = 0; kk < 16; ++kk) {
      float a[4], b[4];
#pragma unroll
      for (int i = 0; i < 4; ++i) a[i] = sm.As[kk][ty * 4 + i];
#pragma unroll
      for (int j = 0; j < 4; ++j) b[j] = sm.Bs[kk][tx * 4 + j];
#pragma unroll
      for (int i = 0; i < 4; ++i)
#pragma unroll
        for (int j = 0; j < 4; ++j) acc[i][j] = fmaf(a[i], b[j], acc[i][j]);
    }
  }
}

// ---------------- 128-tile GEMM (8x8 micro, register prefetch) ---------------
// a-reads are wave-broadcast (free); 64 FMA per 4 b128 LDS reads -> ~2x gemm64 intensity
template <int TA, int TB>
__device__ __forceinline__ void gemm128(const float* __restrict__ A, int lda,
                                        const float* __restrict__ B, int ldb,
                                        int kBeg, int kEnd, float acc[8][8], SMem128& sm) {
  int tid = threadIdx.x, tx = tid & 15, ty = tid >> 4;
  float ra[8], rb[8];
  auto ldAB = [&](int k0) {
#pragma unroll
    for (int q = 0; q < 8; ++q) {
      int e = tid + (q << 8);
      if (TA) { int kk = e >> 7, r = e & 127; ra[q] = A[(size_t)(k0 + kk) * lda + r]; }
      else    { int r = e >> 4, kk = e & 15;  ra[q] = A[(size_t)r * lda + k0 + kk]; }
      if (TB) { int c = e >> 4, kk = e & 15;  rb[q] = B[(size_t)c * ldb + k0 + kk]; }
      else    { int kk = e >> 7, c = e & 127; rb[q] = B[(size_t)(k0 + kk) * ldb + c]; }
    }
  };
  ldAB(kBeg);
  for (int k0 = kBeg; k0 < kEnd; k0 += 16) {
    __syncthreads();
#pragma unroll
    for (int q = 0; q < 8; ++q) {
      int e = tid + (q << 8);
      if (TA) sm.As[e >> 7][e & 127] = ra[q]; else sm.As[e & 15][e >> 4] = ra[q];
      if (TB) sm.Bs[e & 15][e >> 4] = rb[q];  else sm.Bs[e >> 7][e & 127] = rb[q];
    }
    __syncthreads();
    if (k0 + 16 < kEnd) ldAB(k0 + 16);
#pragma unroll
    for (int kk = 0; kk < 16; ++kk) {
      float a[8], b[8];
#pragma unroll
      for (int i = 0; i < 8; ++i) a[i] = sm.As[kk][ty * 8 + i];
#pragma unroll
      for (int j = 0; j < 8; ++j) b[j] = sm.Bs[kk][tx * 8 + j];
#pragma unroll
      for (int i = 0; i < 8; ++i)
#pragma unroll
        for (int j = 0; j < 8; ++j) acc[i][j] = fmaf(a[i], b[j], acc[i][j]);
    }
  }
}

// ---------------- in-LDS 64x64 SPD factor + triangular inverse ---------------
__device__ void factor64(SMem& sm, float* Uout, int ldu) {
  int tid = threadIdx.x;
  int tx = tid & 15, ty = tid >> 4;
  for (int j = 0; j < 63; ++j) {
    float rinv = 1.0f / sm.Ls[j * 65 + j];
    for (int i = j + 1 + ty; i < 64; i += 16) {
      float lij = sm.Ls[i * 65 + j] * rinv;
      for (int c = j + 1 + tx; c <= i; c += 16) sm.Ls[i * 65 + c] -= lij * sm.Ls[c * 65 + j];
    }
    __syncthreads();
  }
  if (tid < 64) sm.dvec[tid] = 1.0f / sqrtf(sm.Ls[tid * 65 + tid]);
  __syncthreads();
  for (int e = tid; e < 4096; e += 256) { int r = e >> 6, c = e & 63; if (c <= r) sm.Ls[r * 65 + c] *= sm.dvec[c]; }
  __syncthreads();
  for (int e = tid; e < 64 * 65; e += 256) sm.Us[e] = 0.0f;
  __syncthreads();
  if (tid < 64) {
    int b = tid >> 5, c0 = tid & 31, base = b * 32, gc = base + c0;
    sm.Us[gc * 65 + gc] = 1.0f / sm.Ls[gc * 65 + gc];
    for (int r = c0 + 1; r < 32; ++r) {
      int gr = base + r;
      float acc = 0.0f;
      for (int l = c0; l < r; ++l) acc += sm.Ls[gr * 65 + base + l] * sm.Us[(base + l) * 65 + gc];
      sm.Us[gr * 65 + gc] = -acc / sm.Ls[gr * 65 + gr];
    }
  }
  __syncthreads();
  for (int e = tid; e < 1024; e += 256) {
    int r = e >> 5, c = e & 31;
    float acc = 0.0f;
    for (int l = c; l < 32; ++l) acc += sm.Ls[(32 + r) * 65 + l] * sm.Us[l * 65 + c];
    sm.Tt[r * 33 + c] = acc;
  }
  __syncthreads();
  for (int e = tid; e < 1024; e += 256) {
    int r = e >> 5, c = e & 31;
    float acc = 0.0f;
    for (int l = 0; l <= r; ++l) acc += sm.Us[(32 + r) * 65 + 32 + l] * sm.Tt[l * 33 + c];
    sm.Us[(32 + r) * 65 + c] = -acc;
  }
  __syncthreads();
  for (int e = tid; e < 4096; e += 256) { int r = e >> 6, c = e & 63; Uout[(size_t)r * ldu + c] = sm.Us[r * 65 + c]; }
}

// ---------------- kernels (job = blockIdx.x, m = blockIdx.y) -----------------

__global__ __launch_bounds__(256) void k_init(float* ws) {
  int t = threadIdx.x;
  float* scal = ws + OFF_SCAL;
  if (t < MM) {
    float* s = scal + t * 32;
    for (int i = 0; i < 12; ++i) s[i] = 0.0f;
    float sp0 = 0.69314718056f;
    s[12] = sp0; s[13] = sp0; s[14] = sp0 + 1e-4f; s[15] = 0.0f;
  }
  if (t < MM * 8) ws[OFF_ACC + t] = 0.0f;
  if (t < MM) ((unsigned*)(ws + OFF_CTR))[t] = 0u;
}

// build K lower tiles; job 0: build tile(0,0) in LDS + factor+invert -> Am.
// job 5 zeroes acc + ticket for this step.
__global__ __launch_bounds__(256) void k_buildK(const float* __restrict__ xc, float* ws, int n) {
  __shared__ SMem sm;
  int job = blockIdx.x, m = blockIdx.y, tid = threadIdx.x;
  const float* xm = xc + (size_t)m * NC * 3;
  float* Km = ws + (size_t)m * 1048576;
  float* Am = ws + OFF_A + (size_t)m * 1048576;
  const float* sT = ws + OFF_SCAL + m * 32;
  float ls = sT[12], os = sT[13], noi = sT[14];
  float il2 = 1.0f / (ls * ls);
  if (job == 5) {
    if (tid < 3) ws[OFF_ACC + m * 8 + tid] = 0.0f;
    if (tid == 3) ((unsigned*)(ws + OFF_CTR))[m] = 0u;
  }
  int bi, bj; lt_decode(job, bi, bj);
  if (tid < 64) {
    int r = bi * 64 + tid;
    sm.xi[tid][0] = xm[r * 3 + 0]; sm.xi[tid][1] = xm[r * 3 + 1]; sm.xi[tid][2] = xm[r * 3 + 2];
  } else if (tid < 128) {
    int lr = tid - 64; int r = bj * 64 + lr;
    sm.xj[lr][0] = xm[r * 3 + 0]; sm.xj[lr][1] = xm[r * 3 + 1]; sm.xj[lr][2] = xm[r * 3 + 2];
  }
  __syncthreads();
  if (job == 0) {
    for (int e = tid; e < 4096; e += 256) {
      int r = e >> 6, c = e & 63;
      float d0 = sm.xi[r][0] - sm.xj[c][0], d1 = sm.xi[r][1] - sm.xj[c][1], d2 = sm.xi[r][2] - sm.xj[c][2];
      float r2 = d0 * d0 + d1 * d1 + d2 * d2;
      float z = fmaxf(r2 * il2, 1e-12f);
      float dd = sqrtf(z);
      float kv = os * (1.0f + S5 * dd + (5.0f / 3.0f) * z) * __expf(-S5 * dd);
      if (r == c) kv += noi;
      sm.Ls[r * 65 + c] = kv;
    }
    __syncthreads();
    factor64(sm, Am, n);
  } else {
    for (int e = tid; e < 4096; e += 256) {
      int r = e >> 6, c = e & 63;
      float d0 = sm.xi[r][0] - sm.xj[c][0], d1 = sm.xi[r][1] - sm.xj[c][1], d2 = sm.xi[r][2] - sm.xj[c][2];
      float r2 = d0 * d0 + d1 * d1 + d2 * d2;
      float z = fmaxf(r2 * il2, 1e-12f);
      float dd = sqrtf(z);
      float kv = os * (1.0f + S5 * dd + (5.0f / 3.0f) * z) * __expf(-S5 * dd);
      if (bi == bj && r == c) kv += noi;
      Km[(size_t)(bi * 64 + r) * n + bj * 64 + c] = kv;
    }
  }
}

// merged panel+trail (64-tile, fused diag factor in job 0) — unchanged from r6
__global__ __launch_bounds__(256) void k_trail(float* ws, int k, int n) {
  __shared__ SMem sm;
  int job = blockIdx.x, m = blockIdx.y, tid = threadIdx.x;
  int tx = tid & 15, ty = tid >> 4;
  float* Km = ws + (size_t)m * 1048576;
  float* Am = ws + OFF_A + (size_t)m * 1048576;
  const float* Linv = Am + (size_t)(k * 64) * n + k * 64;
  int di, dj; lt_decode(job, di, dj);
  int i = k + 1 + di, j = k + 1 + dj;
  float pp[4][4] = {};
  gemm64<0, 1>(Km + (size_t)(i * 64) * n + k * 64, n, Linv, n, 0, 64, pp, sm);
  __syncthreads();
#pragma unroll
  for (int ii = 0; ii < 4; ++ii)
#pragma unroll
    for (int jj = 0; jj < 4; ++jj) sm.Ls[(ty * 4 + ii) * 65 + tx * 4 + jj] = pp[ii][jj];
  if (di == dj) {
    float* P = Am + (size_t)(i * 64) * n + k * 64;
#pragma unroll
    for (int ii = 0; ii < 4; ++ii)
#pragma unroll
      for (int jj = 0; jj < 4; ++jj) P[(size_t)(ty * 4 + ii) * n + tx * 4 + jj] = pp[ii][jj];
  } else {
#pragma unroll
    for (int ii = 0; ii < 4; ++ii)
#pragma unroll
      for (int jj = 0; jj < 4; ++jj) pp[ii][jj] = 0.0f;
    gemm64<0, 1>(Km + (size_t)(j * 64) * n + k * 64, n, Linv, n, 0, 64, pp, sm);
#pragma unroll
    for (int ii = 0; ii < 4; ++ii)
#pragma unroll
      for (int jj = 0; jj < 4; ++jj) sm.Us[(ty * 4 + ii) * 65 + tx * 4 + jj] = pp[ii][jj];
  }
  __syncthreads();
  float acc[4][4] = {};
  {
    const float* Bsrc = (di == dj) ? sm.Ls : sm.Us;
    for (int l = 0; l < 64; ++l) {
      float a[4], b[4];
#pragma unroll
      for (int ii = 0; ii < 4; ++ii) a[ii] = sm.Ls[(ty * 4 + ii) * 65 + l];
#pragma unroll
      for (int jj = 0; jj < 4; ++jj) b[jj] = Bsrc[(tx * 4 + jj) * 65 + l];
#pragma unroll
      for (int ii = 0; ii < 4; ++ii)
#pragma unroll
        for (int jj = 0; jj < 4; ++jj) acc[ii][jj] = fmaf(a[ii], b[jj], acc[ii][jj]);
    }
  }
  float* C = Km + (size_t)(i * 64) * n + j * 64;
  if (job == 0) {
    __syncthreads();
#pragma unroll
    for (int ii = 0; ii < 4; ++ii)
#pragma unroll
      for (int jj = 0; jj < 4; ++jj)
        sm.Ls[(ty * 4 + ii) * 65 + tx * 4 + jj] =
            C[(size_t)(ty * 4 + ii) * n + tx * 4 + jj] - acc[ii][jj];
    __syncthreads();
    factor64(sm, Am + (size_t)((k + 1) * 64) * n + (k + 1) * 64, n);
  } else {
#pragma unroll
    for (int ii = 0; ii < 4; ++ii)
#pragma unroll
      for (int jj = 0; jj < 4; ++jj)
        C[(size_t)(ty * 4 + ii) * n + tx * 4 + jj] -= acc[ii][jj];
  }
}

// fused trinv level s=64 + zero the upper-right 64-subtile of the 128-block
// (makes 128-diag tiles proper block-lower for the 128-grain levels)
__global__ __launch_bounds__(256) void k_trinv64(float* ws, int n) {
  __shared__ SMem sm;
  int p = blockIdx.x, m = blockIdx.y, tid = threadIdx.x;
  int tx = tid & 15, ty = tid >> 4;
  float* Am = ws + OFF_A + (size_t)m * 1048576;
  int rb = (2 * p + 1) * 64, cb = 2 * p * 64;
  for (int e = tid; e < 4096; e += 256) {
    int r = e >> 6, c = e & 63;
    sm.Ls[r * 65 + c] = Am[(size_t)(rb + r) * n + cb + c];  // L21
    sm.Us[r * 65 + c] = Am[(size_t)(cb + r) * n + cb + c];  // A11
    Am[(size_t)(cb + r) * n + rb + c] = 0.0f;               // zero upper-right subtile
  }
  __syncthreads();
  float tt[4][4] = {};
  for (int l = 0; l < 64; ++l) {
    float a[4], b[4];
#pragma unroll
    for (int ii = 0; ii < 4; ++ii) a[ii] = sm.Ls[(ty * 4 + ii) * 65 + l];
#pragma unroll
    for (int jj = 0; jj < 4; ++jj) b[jj] = sm.Us[l * 65 + tx * 4 + jj];
#pragma unroll
    for (int ii = 0; ii < 4; ++ii)
#pragma unroll
      for (int jj = 0; jj < 4; ++jj) tt[ii][jj] = fmaf(a[ii], b[jj], tt[ii][jj]);
  }
  __syncthreads();
#pragma unroll
  for (int ii = 0; ii < 4; ++ii)
#pragma unroll
    for (int jj = 0; jj < 4; ++jj) sm.Ls[(ty * 4 + ii) * 65 + tx * 4 + jj] = tt[ii][jj];
  for (int e = tid; e < 4096; e += 256) {
    int r = e >> 6, c = e & 63;
    sm.Us[r * 65 + c] = Am[(size_t)(rb + r) * n + rb + c];  // A22
  }
  __syncthreads();
  float oo[4][4] = {};
  for (int l = 0; l < 64; ++l) {
    float a[4], b[4];
#pragma unroll
    for (int ii = 0; ii < 4; ++ii) a[ii] = sm.Us[(ty * 4 + ii) * 65 + l];
#pragma unroll
    for (int jj = 0; jj < 4; ++jj) b[jj] = sm.Ls[l * 65 + tx * 4 + jj];
#pragma unroll
    for (int ii = 0; ii < 4; ++ii)
#pragma unroll
      for (int jj = 0; jj < 4; ++jj) oo[ii][jj] = fmaf(a[ii], b[jj], oo[ii][jj]);
  }
#pragma unroll
  for (int ii = 0; ii < 4; ++ii)
#pragma unroll
    for (int jj = 0; jj < 4; ++jj)
      Am[(size_t)(rb + ty * 4 + ii) * n + cb + tx * 4 + jj] = -oo[ii][jj];
}

// trinv levels at 128-grain
__global__ __launch_bounds__(256) void k_trinvT(float* ws, int s, int n) {
  __shared__ SMem128 sm;
  int job = blockIdx.x, m = blockIdx.y;
  int tx = threadIdx.x & 15, ty = threadIdx.x >> 4;
  float* Am = ws + OFF_A + (size_t)m * 1048576;
  float* Tm = ws + OFF_T + (size_t)m * 262144;
  int st = s >> 7;
  int p = job / (st * st), rem = job % (st * st);
  int ti = rem / st, tj = rem % st;
  int base = p * 2 * s;
  float acc[8][8] = {};
  gemm128<0, 0>(Am + (size_t)(base + s + ti * 128) * n + base, n,
                Am + (size_t)base * n + base + tj * 128, n, tj * 128, s, acc, sm);
  float* C = Tm + (size_t)p * s * s + (size_t)(ti * 128) * s + tj * 128;
#pragma unroll
  for (int ii = 0; ii < 8; ++ii)
#pragma unroll
    for (int jj = 0; jj < 8; ++jj) C[(size_t)(ty * 8 + ii) * s + tx * 8 + jj] = acc[ii][jj];
}

__global__ __launch_bounds__(256) void k_trinvA(float* ws, int s, int n) {
  __shared__ SMem128 sm;
  int job = blockIdx.x, m = blockIdx.y;
  int tx = threadIdx.x & 15, ty = threadIdx.x >> 4;
  float* Am = ws + OFF_A + (size_t)m * 1048576;
  const float* Tm = ws + OFF_T + (size_t)m * 262144;
  int st = s >> 7;
  int p = job / (st * st), rem = job % (st * st);
  int ti = rem / st, tj = rem % st;
  int base = p * 2 * s;
  float acc[8][8] = {};
  gemm128<0, 0>(Am + (size_t)(base + s + ti * 128) * n + base + s, n,
                Tm + (size_t)p * s * s + tj * 128, s, 0, (ti + 1) * 128, acc, sm);
  float* C = Am + (size_t)(base + s + ti * 128) * n + base + tj * 128;
#pragma unroll
  for (int ii = 0; ii < 8; ++ii)
#pragma unroll
    for (int jj = 0; jj < 8; ++jj) C[(size_t)(ty * 8 + ii) * n + tx * 8 + jj] = -acc[ii][jj];
}

// alpha stage 1: v = A (y - c), triangular matvec. grid (n/64, MM); v in Tb.
__global__ __launch_bounds__(256) void k_alpha1(const float* __restrict__ yc, float* ws, int n) {
  int m = blockIdx.y, tid = threadIdx.x;
  int r0 = blockIdx.x * 64;
  int w = tid >> 6, lane = tid & 63;
  const float* Am = ws + OFF_A + (size_t)m * 1048576;
  const float* ym = yc + (size_t)m * NC;
  float* v = ws + OFF_T + (size_t)m * 262144;
  float cm = ws[OFF_SCAL + m * 32 + 15];
  for (int rr = 0; rr < 16; ++rr) {
    int i = r0 + rr * 4 + w;
    float sum = 0.0f;
    const float* row = Am + (size_t)i * n;
    for (int j = lane; j <= i; j += 64) sum = fmaf(row[j], ym[j] - cm, sum);
    for (int off = 32; off; off >>= 1) sum += __shfl_down(sum, off);
    if (lane == 0) v[i] = sum;
  }
}

// alpha stage 2: alpha = A^T v. grid (n/64, MM).
__global__ __launch_bounds__(256) void k_alpha2(float* ws, int n) {
  __shared__ float red2[4][64];
  int m = blockIdx.y, tid = threadIdx.x;
  int c0 = blockIdx.x * 64;
  int w = tid >> 6, lane = tid & 63;
  const float* Am = ws + OFF_A + (size_t)m * 1048576;
  const float* v = ws + OFF_T + (size_t)m * 262144;
  float* al = ws + OFF_ALPHA + (size_t)m * 1024;
  int j = c0 + lane;
  float part = 0.0f;
  for (int i = c0 + w; i < n; i += 4) {
    float vi = v[i];
    if (j <= i) part = fmaf(Am[(size_t)i * n + j], vi, part);
  }
  red2[w][lane] = part;
  __syncthreads();
  if (tid < 64) al[c0 + tid] = red2[0][tid] + red2[1][tid] + red2[2][tid] + red2[3][tid];
}

// syrk (128-tile) with fused T1/T2/trG reduction + last-block Adam.
// Training (step<16): no G write. Final (step==16): writes G, skips eval/adam.
__global__ __launch_bounds__(256) void k_syrkATR(const float* __restrict__ yc,
                                                 const float* __restrict__ xc,
                                                 float* ws, int n, int step) {
  __shared__ SMem128 sm;
  __shared__ unsigned tkt;
  int job = blockIdx.x, m = blockIdx.y, tid = threadIdx.x;
  int tx = tid & 15, ty = tid >> 4;
  const float* Am = ws + OFF_A + (size_t)m * 1048576;
  float* Gm = ws + (size_t)m * 1048576;
  float* sT = ws + OFF_SCAL + m * 32;
  float* accp = ws + OFF_ACC + m * 8;
  const float* al = ws + OFF_ALPHA + (size_t)m * 1024;
  const float* xm = xc + (size_t)m * NC * 3;
  const float* ym = yc + (size_t)m * NC;
  int train = (step < 16);
  int nb128 = n >> 7;
  int njobs = nb128 * (nb128 + 1) / 2;
  int ib, jb; lt_decode(job, ib, jb);
  float ls = sT[12], os = sT[13];
  if (train) {
    if (tid < 128) {
      int r = ib * 128 + tid;
      sm.xi[tid][0] = xm[r * 3 + 0]; sm.xi[tid][1] = xm[r * 3 + 1]; sm.xi[tid][2] = xm[r * 3 + 2];
      sm.ai[tid] = al[r];
    } else {
      int lr = tid - 128; int r = jb * 128 + lr;
      sm.xj[lr][0] = xm[r * 3 + 0]; sm.xj[lr][1] = xm[r * 3 + 1]; sm.xj[lr][2] = xm[r * 3 + 2];
      sm.aj[lr] = al[r];
    }
  }
  float acc[8][8] = {};
  gemm128<1, 0>(Am + ib * 128, n, Am + jb * 128, n, ib * 128, n, acc, sm);
  if (!train) {
#pragma unroll
    for (int ii = 0; ii < 8; ++ii)
#pragma unroll
      for (int jj = 0; jj < 8; ++jj) {
        int r = ty * 8 + ii, c = tx * 8 + jj;
        Gm[(size_t)(ib * 128 + r) * n + jb * 128 + c] = acc[ii][jj];
        if (ib != jb) Gm[(size_t)(jb * 128 + c) * n + ib * 128 + r] = acc[ii][jj];
      }
    return;
  }
  // fused reduce: T1 = <G,C>, T2 = alpha^T C alpha, trG — all from registers/LDS
  float il2 = 1.0f / (ls * ls);
  float c53 = (5.0f / 3.0f) * os / ls;
  float w = (ib == jb) ? 1.0f : 2.0f;
  float a1 = 0.0f, a2 = 0.0f, a3 = 0.0f;
#pragma unroll
  for (int ii = 0; ii < 8; ++ii) {
    int r = ty * 8 + ii;
    float x0 = sm.xi[r][0], x1 = sm.xi[r][1], x2 = sm.xi[r][2], ar = sm.ai[r];
#pragma unroll
    for (int jj = 0; jj < 8; ++jj) {
      int c = tx * 8 + jj;
      float d0 = x0 - sm.xj[c][0], d1 = x1 - sm.xj[c][1], d2 = x2 - sm.xj[c][2];
      float r2 = d0 * d0 + d1 * d1 + d2 * d2;
      float z = fmaxf(r2 * il2, 1e-12f);
      float dd = sqrtf(z);
      float Cv = c53 * z * (1.0f + S5 * dd) * __expf(-S5 * dd);
      a1 = fmaf(acc[ii][jj], Cv, a1);
      a2 = fmaf(ar * sm.aj[c], Cv, a2);
    }
    if (ib == jb && tx == ty) a3 += acc[ii][ii];
  }
  a1 *= w; a2 *= w;
  for (int off = 32; off; off >>= 1) {
    a1 += __shfl_down(a1, off); a2 += __shfl_down(a2, off); a3 += __shfl_down(a3, off);
  }
  int wid = tid >> 6, lane = tid & 63;
  __syncthreads();
  if (lane == 0) { sm.red[wid][0] = a1; sm.red[wid][1] = a2; sm.red[wid][2] = a3; }
  __syncthreads();
  if (tid == 0) {
    a1 = sm.red[0][0] + sm.red[1][0] + sm.red[2][0] + sm.red[3][0];
    a2 = sm.red[0][1] + sm.red[1][1] + sm.red[2][1] + sm.red[3][1];
    a3 = sm.red[0][2] + sm.red[1][2] + sm.red[2][2] + sm.red[3][2];
    atomicAdd(&accp[0], a1);
    atomicAdd(&accp[1], a2);
    if (ib == jb) atomicAdd(&accp[2], a3);
  }
  // completion ticket; last block runs Adam inline
  __threadfence();
  if (tid == 0)
    tkt = __hip_atomic_fetch_add((unsigned*)(ws + OFF_CTR) + m, 1u,
                                 __ATOMIC_ACQ_REL, __HIP_MEMORY_SCOPE_AGENT);
  __syncthreads();
  if (tkt != (unsigned)(njobs - 1)) return;
  float cm = sT[15];
  float t4 = 0, t5 = 0, t6 = 0;
  for (int i = tid; i < n; i += 256) {
    float a = al[i];
    t4 = fmaf(a, a, t4); t5 += a; t6 = fmaf(ym[i] - cm, a, t6);
  }
  for (int off = 32; off; off >>= 1) {
    t4 += __shfl_down(t4, off); t5 += __shfl_down(t5, off); t6 += __shfl_down(t6, off);
  }
  __syncthreads();
  if (lane == 0) { sm.red[wid][0] = t4; sm.red[wid][1] = t5; sm.red[wid][2] = t6; }
  __syncthreads();
  if (tid == 0) {
    t4 = sm.red[0][0] + sm.red[1][0] + sm.red[2][0] + sm.red[3][0];
    t5 = sm.red[0][1] + sm.red[1][1] + sm.red[2][1] + sm.red[3][1];
    t6 = sm.red[0][2] + sm.red[1][2] + sm.red[2][2] + sm.red[3][2];
    float T1 = __hip_atomic_fetch_add(&accp[0], 0.0f, __ATOMIC_RELAXED, __HIP_MEMORY_SCOPE_AGENT);
    float T2 = __hip_atomic_fetch_add(&accp[1], 0.0f, __ATOMIC_RELAXED, __HIP_MEMORY_SCOPE_AGENT);
    float t3 = __hip_atomic_fetch_add(&accp[2], 0.0f, __ATOMIC_RELAXED, __HIP_MEMORY_SCOPE_AGENT);
    float noi = sT[14];
    float fn = (float)n;
    float g_ls = 0.5f / fn * (T1 - T2);
    float g_os = 0.5f / (fn * os) * (fn - noi * t3 - t6 + noi * t4);
    float g_no = 0.5f / fn * (t3 - t4);
    float g_c = -t5 / fn;
    float gr[4];
    gr[0] = g_ls * sigmf(sT[0]);
    gr[1] = g_os * sigmf(sT[1]);
    gr[2] = g_no * sigmf(sT[2]);
    gr[3] = g_c;
    int tstep = step + 1;
    float bc1 = 1.0f - powf(0.9f, (float)tstep);
    float bc2 = 1.0f - powf(0.999f, (float)tstep);
#pragma unroll
    for (int i = 0; i < 4; ++i) {
      float mv = 0.9f * sT[4 + i] + 0.1f * gr[i];
      float vv = 0.999f * sT[8 + i] + 0.001f * gr[i] * gr[i];
      sT[4 + i] = mv; sT[8 + i] = vv;
      sT[i] = sT[i] - 0.1f * (mv / bc1) / (sqrtf(vv / bc2) + 1e-8f);
    }
    sT[12] = softplusf(sT[0]);
    sT[13] = softplusf(sT[1]);
    sT[14] = softplusf(sT[2]) + 1e-4f;
    sT[15] = sT[3];
  }
}

// prediction: build Ktc (64-tile) + zero S1/S2
__global__ __launch_bounds__(256) void k_buildKtc(const float* __restrict__ xt,
                                                  const float* __restrict__ xc, float* ws) {
  __shared__ SMem sm;
  int job = blockIdx.x, m = blockIdx.y, tid = threadIdx.x;
  const float* xtm = xt + (size_t)m * NT * 3;
  const float* xm = xc + (size_t)m * NC * 3;
  float* Kt = ws + OFF_KTC + (size_t)m * NT * NC;
  float* Tm = ws + OFF_T + (size_t)m * 262144;  // S1 at Tm, S2 at Tm+NT
  const float* sT = ws + OFF_SCAL + m * 32;
  float ls = sT[12], os = sT[13];
  float il2 = 1.0f / (ls * ls);
  if (job < 2) {
    int z = job * 256 + tid;
    Tm[z] = 0.0f; Tm[NT + z] = 0.0f;
  }
  int ti = job >> 4, tj = job & 15;
  if (tid < 64) {
    int r = ti * 64 + tid;
    sm.xi[tid][0] = xtm[r * 3 + 0]; sm.xi[tid][1] = xtm[r * 3 + 1]; sm.xi[tid][2] = xtm[r * 3 + 2];
  } else if (tid < 128) {
    int lr = tid - 64; int r = tj * 64 + lr;
    sm.xj[lr][0] = xm[r * 3 + 0]; sm.xj[lr][1] = xm[r * 3 + 1]; sm.xj[lr][2] = xm[r * 3 + 2];
  }
  __syncthreads();
  for (int e = tid; e < 4096; e += 256) {
    int r = e >> 6, c = e & 63;
    float d0 = sm.xi[r][0] - sm.xj[c][0], d1 = sm.xi[r][1] - sm.xj[c][1], d2 = sm.xi[r][2] - sm.xj[c][2];
    float r2 = d0 * d0 + d1 * d1 + d2 * d2;
    float z = fmaxf(r2 * il2, 1e-12f);
    float dd = sqrtf(z);
    float kv = os * (1.0f + S5 * dd + (5.0f / 3.0f) * z) * __expf(-S5 * dd);
    Kt[(size_t)(ti * 64 + r) * NC + tj * 64 + c] = kv;
  }
}

// predW (128-tile): W = Ktc*G in-register; fused S1 += Ktc.alpha, S2 += Ktc.W
__global__ __launch_bounds__(256) void k_predW(float* ws) {
  __shared__ SMem128 sm;
  int job = blockIdx.x, m = blockIdx.y, tid = threadIdx.x;
  int tx = tid & 15, ty = tid >> 4;
  const float* Kt = ws + OFF_KTC + (size_t)m * NT * NC;
  const float* Gm = ws + (size_t)m * 1048576;
  const float* al = ws + OFF_ALPHA + (size_t)m * 1024;
  float* S1 = ws + OFF_T + (size_t)m * 262144;
  float* S2 = S1 + NT;
  int ti = job >> 3, tj = job & 7;   // 4 x 8 tiles of 128
  if (tid < 128) sm.ai[tid] = al[tj * 128 + tid];
  float acc[8][8] = {};
  gemm128<0, 0>(Kt + (size_t)(ti * 128) * NC, NC, Gm + tj * 128, 1024, 0, 1024, acc, sm);
  float s1p[8], s2p[8];
#pragma unroll
  for (int ii = 0; ii < 8; ++ii) {
    float a1 = 0.0f, a2 = 0.0f;
    const float* kr = Kt + (size_t)(ti * 128 + ty * 8 + ii) * NC + tj * 128;
#pragma unroll
    for (int jj = 0; jj < 8; ++jj) {
      float kv = kr[tx * 8 + jj];
      a1 = fmaf(kv, sm.ai[tx * 8 + jj], a1);
      a2 = fmaf(kv, acc[ii][jj], a2);
    }
    s1p[ii] = a1; s2p[ii] = a2;
  }
  __syncthreads();
  float* redA = &sm.As[0][0];   // 128 x 16
  float* redB = &sm.Bs[0][0];
#pragma unroll
  for (int ii = 0; ii < 8; ++ii) {
    redA[(ty * 8 + ii) * 16 + tx] = s1p[ii];
    redB[(ty * 8 + ii) * 16 + tx] = s2p[ii];
  }
  __syncthreads();
  if (tid < 128) {
    float a1 = 0.0f, a2 = 0.0f;
#pragma unroll
    for (int q = 0; q < 16; ++q) { a1 += redA[tid * 16 + q]; a2 += redB[tid * 16 + q]; }
    atomicAdd(&S1[ti * 128 + tid], a1);
    atomicAdd(&S2[ti * 128 + tid], a2);
  }
}

__global__ __launch_bounds__(256) void k_final(float* ws, float* out) {
  int m = blockIdx.y, t = blockIdx.x * 256 + threadIdx.x;
  const float* S1 = ws + OFF_T + (size_t)m * 262144;
  const float* S2 = S1 + NT;
  const float* sT = ws + OFF_SCAL + m * 32;
  if (t < NT) {
    out[(size_t)m * NT + t] = sT[15] + S1[t];
    out[(size_t)MM * NT + (size_t)m * NT + t] = sT[13] + sT[14] - S2[t];
  }
}

// ---------------- host: discrete graph pipeline ------------------------------
extern "C" void kernel_launch(void* const* d_in, const int* in_sizes, int n_in,
                              void* d_out, int out_size, void* d_ws, size_t ws_size,
                              hipStream_t stream) {
  const float* xc = (const float*)d_in[0];
  const float* yc = (const float*)d_in[1];
  const float* xt = (const float*)d_in[2];
  float* out = (float*)d_out;
  float* ws = (float*)d_ws;

  k_init<<<dim3(1), dim3(256), 0, stream>>>(ws);

  for (int step = 0; step < 17; ++step) {
    int n = step < 8 ? 512 : 1024;
    int nb = n >> 6;
    k_buildK<<<dim3(nb * (nb + 1) / 2, MM), dim3(256), 0, stream>>>(xc, ws, n);
    for (int k = 0; k <= nb - 2; ++k) {
      int t = nb - 1 - k;
      k_trail<<<dim3(t * (t + 1) / 2, MM), dim3(256), 0, stream>>>(ws, k, n);
    }
    k_trinv64<<<dim3(n / 128, MM), dim3(256), 0, stream>>>(ws, n);
    for (int s = 128; s < n; s <<= 1) {
      int st = s >> 7, np = n / (2 * s);
      k_trinvT<<<dim3(np * st * st, MM), dim3(256), 0, stream>>>(ws, s, n);
      k_trinvA<<<dim3(np * st * st, MM), dim3(256), 0, stream>>>(ws, s, n);
    }
    k_alpha1<<<dim3(n / 64, MM), dim3(256), 0, stream>>>(yc, ws, n);
    k_alpha2<<<dim3(n / 64, MM), dim3(256), 0, stream>>>(ws, n);
    int nb128 = n >> 7;
    k_syrkATR<<<dim3(nb128 * (nb128 + 1) / 2, MM), dim3(256), 0, stream>>>(yc, xc, ws, n, step);
  }

  k_buildKtc<<<dim3(128, MM), dim3(256), 0, stream>>>(xt, xc, ws);
  k_predW<<<dim3(32, MM), dim3(256), 0, stream>>>(ws);
  k_final<<<dim3(2, MM), dim3(256), 0, stream>>>(ws, out);

  (void)in_sizes; (void)n_in; (void)out_size; (void)ws_size;
}

// Round 8
// 20510.295 us; speedup vs baseline: 1.2294x; 1.2294x over previous
//
#include <hip/hip_runtime.h>
#include <math.h>

// ---------------- problem constants ----------------
constexpr int MM = 8;      // batch of GPs
constexpr int NC = 1024;   // context points
constexpr int NT = 512;    // target points

// Workspace (floats):
//  Kb   : MM*1024*1024   (K raw/Schur -> G = K^-1 after syrk)
//  Ab   : MM*1024*1024   (diag-block inverses + L panels -> A = L^-1)
//  Tb   : MM*512*512     (trinv temp; S1/S2 accumulators at predict)
//  Ktc  : MM*NT*NC
//  alpha: MM*1024
//  scal : MM*32  ([0..3] raw, [4..7] adam m, [8..11] adam v, [12]ls [13]os [14]noi [15]cm)
//  acc  : MM*8   ([T1, T2, trG] per m)
//  ctr  : MM u32 (reduce completion tickets)
constexpr size_t OFF_A     = (size_t)MM * 1024 * 1024;
constexpr size_t OFF_T     = OFF_A * 2;
constexpr size_t OFF_KTC   = OFF_T + (size_t)MM * 512 * 512;
constexpr size_t OFF_ALPHA = OFF_KTC + (size_t)MM * NT * NC;
constexpr size_t OFF_SCAL  = OFF_ALPHA + (size_t)MM * 1024;
constexpr size_t OFF_ACC   = OFF_SCAL + (size_t)MM * 32;
constexpr size_t OFF_CTR   = OFF_ACC + (size_t)MM * 8;

#define S5 2.2360679775f

__device__ __forceinline__ float sigmf(float x) { return 1.0f / (1.0f + expf(-x)); }
__device__ __forceinline__ float softplusf(float x) { return fmaxf(x, 0.0f) + log1pf(expf(-fabsf(x))); }

__device__ __forceinline__ void lt_decode(int x, int& i, int& j) {
  int ii = 0;
  while ((ii + 1) * (ii + 2) / 2 <= x) ++ii;
  i = ii; j = x - ii * (ii + 1) / 2;
}

// Shared-memory struct (~47.5 KB)
struct SMem {
  float Ls[64 * 65];
  float Us[64 * 65];
  float Tt[32 * 33];
  float dvec[64];
  float As[16][68];
  float Bs[16][68];
  float xi[64][3];
  float xj[64][3];
  float ai[64];
  float aj[64];
  float red[4][4];
};

// ---------------- 64-tile GEMM (4x4 micro, register prefetch) ----------------
template <int TA, int TB>
__device__ __forceinline__ void gemm64(const float* __restrict__ A, int lda,
                                       const float* __restrict__ B, int ldb,
                                       int kBeg, int kEnd, float acc[4][4], SMem& sm) {
  int tid = threadIdx.x, tx = tid & 15, ty = tid >> 4;
  float ra[4], rb[4];
  auto ldAB = [&](int k0) {
#pragma unroll
    for (int q = 0; q < 4; ++q) {
      int e = tid + (q << 8);
      if (TA) { int kk = e >> 6, r = e & 63; ra[q] = A[(size_t)(k0 + kk) * lda + r]; }
      else    { int r = e >> 4, kk = e & 15; ra[q] = A[(size_t)r * lda + k0 + kk]; }
      if (TB) { int c = e >> 4, kk = e & 15; rb[q] = B[(size_t)c * ldb + k0 + kk]; }
      else    { int kk = e >> 6, c = e & 63; rb[q] = B[(size_t)(k0 + kk) * ldb + c]; }
    }
  };
  ldAB(kBeg);
  for (int k0 = kBeg; k0 < kEnd; k0 += 16) {
    __syncthreads();
#pragma unroll
    for (int q = 0; q < 4; ++q) {
      int e = tid + (q << 8);
      if (TA) sm.As[e >> 6][e & 63] = ra[q]; else sm.As[e & 15][e >> 4] = ra[q];
      if (TB) sm.Bs[e & 15][e >> 4] = rb[q]; else sm.Bs[e >> 6][e & 63] = rb[q];
    }
    __syncthreads();
    if (k0 + 16 < kEnd) ldAB(k0 + 16);
#pragma unroll
    for (int kk = 0; kk < 16; ++kk) {
      float a[4], b[4];
#pragma unroll
      for (int i = 0; i < 4; ++i) a[i] = sm.As[kk][ty * 4 + i];
#pragma unroll
      for (int j = 0; j < 4; ++j) b[j] = sm.Bs[kk][tx * 4 + j];
#pragma unroll
      for (int i = 0; i < 4; ++i)
#pragma unroll
        for (int j = 0; j < 4; ++j) acc[i][j] = fmaf(a[i], b[j], acc[i][j]);
    }
  }
}

// ---------------- in-LDS 64x64 SPD factor + triangular inverse ---------------
__device__ void factor64(SMem& sm, float* Uout, int ldu) {
  int tid = threadIdx.x;
  int tx = tid & 15, ty = tid >> 4;
  for (int j = 0; j < 63; ++j) {
    float rinv = 1.0f / sm.Ls[j * 65 + j];
    for (int i = j + 1 + ty; i < 64; i += 16) {
      float lij = sm.Ls[i * 65 + j] * rinv;
      for (int c = j + 1 + tx; c <= i; c += 16) sm.Ls[i * 65 + c] -= lij * sm.Ls[c * 65 + j];
    }
    __syncthreads();
  }
  if (tid < 64) sm.dvec[tid] = 1.0f / sqrtf(sm.Ls[tid * 65 + tid]);
  __syncthreads();
  for (int e = tid; e < 4096; e += 256) { int r = e >> 6, c = e & 63; if (c <= r) sm.Ls[r * 65 + c] *= sm.dvec[c]; }
  __syncthreads();
  for (int e = tid; e < 64 * 65; e += 256) sm.Us[e] = 0.0f;
  __syncthreads();
  if (tid < 64) {
    int b = tid >> 5, c0 = tid & 31, base = b * 32, gc = base + c0;
    sm.Us[gc * 65 + gc] = 1.0f / sm.Ls[gc * 65 + gc];
    for (int r = c0 + 1; r < 32; ++r) {
      int gr = base + r;
      float acc = 0.0f;
      for (int l = c0; l < r; ++l) acc += sm.Ls[gr * 65 + base + l] * sm.Us[(base + l) * 65 + gc];
      sm.Us[gr * 65 + gc] = -acc / sm.Ls[gr * 65 + gr];
    }
  }
  __syncthreads();
  for (int e = tid; e < 1024; e += 256) {
    int r = e >> 5, c = e & 31;
    float acc = 0.0f;
    for (int l = c; l < 32; ++l) acc += sm.Ls[(32 + r) * 65 + l] * sm.Us[l * 65 + c];
    sm.Tt[r * 33 + c] = acc;
  }
  __syncthreads();
  for (int e = tid; e < 1024; e += 256) {
    int r = e >> 5, c = e & 31;
    float acc = 0.0f;
    for (int l = 0; l <= r; ++l) acc += sm.Us[(32 + r) * 65 + 32 + l] * sm.Tt[l * 33 + c];
    sm.Us[(32 + r) * 65 + c] = -acc;
  }
  __syncthreads();
  for (int e = tid; e < 4096; e += 256) { int r = e >> 6, c = e & 63; Uout[(size_t)r * ldu + c] = sm.Us[r * 65 + c]; }
}

// ---------------- discrete kernels (job = blockIdx.x, m = blockIdx.y) --------

__global__ __launch_bounds__(256) void k_init(float* ws) {
  int t = threadIdx.x;
  float* scal = ws + OFF_SCAL;
  float* acc = ws + OFF_ACC;
  if (t < MM) {
    float* s = scal + t * 32;
    for (int i = 0; i < 12; ++i) s[i] = 0.0f;
    float sp0 = 0.69314718056f;
    s[12] = sp0; s[13] = sp0; s[14] = sp0 + 1e-4f; s[15] = 0.0f;
  }
  if (t < MM * 8) acc[t] = 0.0f;
  if (t < MM) ((unsigned*)(ws + OFF_CTR))[t] = 0u;
}

// build K lower tiles; job 0: build tile(0,0) in LDS + factor+invert ->Am.
// side tasks: jobs 1..4 zero alpha, job 5 zeroes acc + ticket.
__global__ __launch_bounds__(256) void k_buildK(const float* __restrict__ xc, float* ws, int n) {
  __shared__ SMem sm;
  int job = blockIdx.x, m = blockIdx.y, tid = threadIdx.x;
  const float* xm = xc + (size_t)m * NC * 3;
  float* Km = ws + (size_t)m * 1048576;
  float* Am = ws + OFF_A + (size_t)m * 1048576;
  const float* sT = ws + OFF_SCAL + m * 32;
  float ls = sT[12], os = sT[13], noi = sT[14];
  float il2 = 1.0f / (ls * ls);
  if (job >= 1 && job <= 4) {
    int zi = (job - 1) * 256 + tid;
    if (zi < n) ws[OFF_ALPHA + (size_t)m * 1024 + zi] = 0.0f;
  }
  if (job == 5) {
    if (tid < 4) ws[OFF_ACC + m * 8 + tid] = 0.0f;
    if (tid == 4) ((unsigned*)(ws + OFF_CTR))[m] = 0u;
  }
  int bi, bj; lt_decode(job, bi, bj);
  if (tid < 64) {
    int r = bi * 64 + tid;
    sm.xi[tid][0] = xm[r * 3 + 0]; sm.xi[tid][1] = xm[r * 3 + 1]; sm.xi[tid][2] = xm[r * 3 + 2];
  } else if (tid < 128) {
    int lr = tid - 64; int r = bj * 64 + lr;
    sm.xj[lr][0] = xm[r * 3 + 0]; sm.xj[lr][1] = xm[r * 3 + 1]; sm.xj[lr][2] = xm[r * 3 + 2];
  }
  __syncthreads();
  if (job == 0) {
    for (int e = tid; e < 4096; e += 256) {
      int r = e >> 6, c = e & 63;
      float d0 = sm.xi[r][0] - sm.xj[c][0], d1 = sm.xi[r][1] - sm.xj[c][1], d2 = sm.xi[r][2] - sm.xj[c][2];
      float r2 = d0 * d0 + d1 * d1 + d2 * d2;
      float z = fmaxf(r2 * il2, 1e-12f);
      float dd = sqrtf(z);
      float kv = os * (1.0f + S5 * dd + (5.0f / 3.0f) * z) * __expf(-S5 * dd);
      if (r == c) kv += noi;
      sm.Ls[r * 65 + c] = kv;
    }
    __syncthreads();
    factor64(sm, Am, n);
  } else {
    for (int e = tid; e < 4096; e += 256) {
      int r = e >> 6, c = e & 63;
      float d0 = sm.xi[r][0] - sm.xj[c][0], d1 = sm.xi[r][1] - sm.xj[c][1], d2 = sm.xi[r][2] - sm.xj[c][2];
      float r2 = d0 * d0 + d1 * d1 + d2 * d2;
      float z = fmaxf(r2 * il2, 1e-12f);
      float dd = sqrtf(z);
      float kv = os * (1.0f + S5 * dd + (5.0f / 3.0f) * z) * __expf(-S5 * dd);
      if (bi == bj && r == c) kv += noi;
      Km[(size_t)(bi * 64 + r) * n + bj * 64 + c] = kv;
    }
  }
}

// merged panel+trail: job (di,dj) recomputes P_i=K[i,k]*Linv^T (and P_j),
// K[i,j] -= P_i P_j^T. di==dj stores P_i panel into Ab. job 0: LDS Schur +
// factor+invert of tile (k+1,k+1).
__global__ __launch_bounds__(256) void k_trail(float* ws, int k, int n) {
  __shared__ SMem sm;
  int job = blockIdx.x, m = blockIdx.y, tid = threadIdx.x;
  int tx = tid & 15, ty = tid >> 4;
  float* Km = ws + (size_t)m * 1048576;
  float* Am = ws + OFF_A + (size_t)m * 1048576;
  const float* Linv = Am + (size_t)(k * 64) * n + k * 64;
  int di, dj; lt_decode(job, di, dj);
  int i = k + 1 + di, j = k + 1 + dj;
  float pp[4][4] = {};
  gemm64<0, 1>(Km + (size_t)(i * 64) * n + k * 64, n, Linv, n, 0, 64, pp, sm);
  __syncthreads();
#pragma unroll
  for (int ii = 0; ii < 4; ++ii)
#pragma unroll
    for (int jj = 0; jj < 4; ++jj) sm.Ls[(ty * 4 + ii) * 65 + tx * 4 + jj] = pp[ii][jj];
  if (di == dj) {
    float* P = Am + (size_t)(i * 64) * n + k * 64;
#pragma unroll
    for (int ii = 0; ii < 4; ++ii)
#pragma unroll
      for (int jj = 0; jj < 4; ++jj) P[(size_t)(ty * 4 + ii) * n + tx * 4 + jj] = pp[ii][jj];
  } else {
#pragma unroll
    for (int ii = 0; ii < 4; ++ii)
#pragma unroll
      for (int jj = 0; jj < 4; ++jj) pp[ii][jj] = 0.0f;
    gemm64<0, 1>(Km + (size_t)(j * 64) * n + k * 64, n, Linv, n, 0, 64, pp, sm);
#pragma unroll
    for (int ii = 0; ii < 4; ++ii)
#pragma unroll
      for (int jj = 0; jj < 4; ++jj) sm.Us[(ty * 4 + ii) * 65 + tx * 4 + jj] = pp[ii][jj];
  }
  __syncthreads();
  float acc[4][4] = {};
  {
    const float* Bsrc = (di == dj) ? sm.Ls : sm.Us;
    for (int l = 0; l < 64; ++l) {
      float a[4], b[4];
#pragma unroll
      for (int ii = 0; ii < 4; ++ii) a[ii] = sm.Ls[(ty * 4 + ii) * 65 + l];
#pragma unroll
      for (int jj = 0; jj < 4; ++jj) b[jj] = Bsrc[(tx * 4 + jj) * 65 + l];
#pragma unroll
      for (int ii = 0; ii < 4; ++ii)
#pragma unroll
        for (int jj = 0; jj < 4; ++jj) acc[ii][jj] = fmaf(a[ii], b[jj], acc[ii][jj]);
    }
  }
  float* C = Km + (size_t)(i * 64) * n + j * 64;
  if (job == 0) {
    __syncthreads();
#pragma unroll
    for (int ii = 0; ii < 4; ++ii)
#pragma unroll
      for (int jj = 0; jj < 4; ++jj)
        sm.Ls[(ty * 4 + ii) * 65 + tx * 4 + jj] =
            C[(size_t)(ty * 4 + ii) * n + tx * 4 + jj] - acc[ii][jj];
    __syncthreads();
    factor64(sm, Am + (size_t)((k + 1) * 64) * n + (k + 1) * 64, n);
  } else {
#pragma unroll
    for (int ii = 0; ii < 4; ++ii)
#pragma unroll
      for (int jj = 0; jj < 4; ++jj)
        C[(size_t)(ty * 4 + ii) * n + tx * 4 + jj] -= acc[ii][jj];
  }
}

// fused trinv level s=64: per pair p, T = L21*A11 then A21 = -A22*T
__global__ __launch_bounds__(256) void k_trinv64(float* ws, int n) {
  __shared__ SMem sm;
  int p = blockIdx.x, m = blockIdx.y, tid = threadIdx.x;
  int tx = tid & 15, ty = tid >> 4;
  float* Am = ws + OFF_A + (size_t)m * 1048576;
  int rb = (2 * p + 1) * 64, cb = 2 * p * 64;
  for (int e = tid; e < 4096; e += 256) {
    int r = e >> 6, c = e & 63;
    sm.Ls[r * 65 + c] = Am[(size_t)(rb + r) * n + cb + c];  // L21
    sm.Us[r * 65 + c] = Am[(size_t)(cb + r) * n + cb + c];  // A11
  }
  __syncthreads();
  float tt[4][4] = {};
  for (int l = 0; l < 64; ++l) {
    float a[4], b[4];
#pragma unroll
    for (int ii = 0; ii < 4; ++ii) a[ii] = sm.Ls[(ty * 4 + ii) * 65 + l];
#pragma unroll
    for (int jj = 0; jj < 4; ++jj) b[jj] = sm.Us[l * 65 + tx * 4 + jj];
#pragma unroll
    for (int ii = 0; ii < 4; ++ii)
#pragma unroll
      for (int jj = 0; jj < 4; ++jj) tt[ii][jj] = fmaf(a[ii], b[jj], tt[ii][jj]);
  }
  __syncthreads();
#pragma unroll
  for (int ii = 0; ii < 4; ++ii)
#pragma unroll
    for (int jj = 0; jj < 4; ++jj) sm.Ls[(ty * 4 + ii) * 65 + tx * 4 + jj] = tt[ii][jj];
  for (int e = tid; e < 4096; e += 256) {
    int r = e >> 6, c = e & 63;
    sm.Us[r * 65 + c] = Am[(size_t)(rb + r) * n + rb + c];  // A22
  }
  __syncthreads();
  float oo[4][4] = {};
  for (int l = 0; l < 64; ++l) {
    float a[4], b[4];
#pragma unroll
    for (int ii = 0; ii < 4; ++ii) a[ii] = sm.Us[(ty * 4 + ii) * 65 + l];
#pragma unroll
    for (int jj = 0; jj < 4; ++jj) b[jj] = sm.Ls[l * 65 + tx * 4 + jj];
#pragma unroll
    for (int ii = 0; ii < 4; ++ii)
#pragma unroll
      for (int jj = 0; jj < 4; ++jj) oo[ii][jj] = fmaf(a[ii], b[jj], oo[ii][jj]);
  }
#pragma unroll
  for (int ii = 0; ii < 4; ++ii)
#pragma unroll
    for (int jj = 0; jj < 4; ++jj)
      Am[(size_t)(rb + ty * 4 + ii) * n + cb + tx * 4 + jj] = -oo[ii][jj];
}

__global__ __launch_bounds__(256) void k_trinvT(float* ws, int s, int n) {
  __shared__ SMem sm;
  int job = blockIdx.x, m = blockIdx.y;
  int tx = threadIdx.x & 15, ty = threadIdx.x >> 4;
  float* Am = ws + OFF_A + (size_t)m * 1048576;
  float* Tm = ws + OFF_T + (size_t)m * 262144;
  int st = s >> 6;
  int p = job / (st * st), rem = job % (st * st);
  int ti = rem / st, tj = rem % st;
  int base = p * 2 * s;
  float acc[4][4] = {};
  gemm64<0, 0>(Am + (size_t)(base + s + ti * 64) * n + base, n,
               Am + (size_t)base * n + base + tj * 64, n, tj * 64, s, acc, sm);
  float* C = Tm + (size_t)p * s * s + (size_t)(ti * 64) * s + tj * 64;
#pragma unroll
  for (int ii = 0; ii < 4; ++ii)
#pragma unroll
    for (int jj = 0; jj < 4; ++jj) C[(size_t)(ty * 4 + ii) * s + tx * 4 + jj] = acc[ii][jj];
}

__global__ __launch_bounds__(256) void k_trinvA(float* ws, int s, int n) {
  __shared__ SMem sm;
  int job = blockIdx.x, m = blockIdx.y;
  int tx = threadIdx.x & 15, ty = threadIdx.x >> 4;
  float* Am = ws + OFF_A + (size_t)m * 1048576;
  const float* Tm = ws + OFF_T + (size_t)m * 262144;
  int st = s >> 6;
  int p = job / (st * st), rem = job % (st * st);
  int ti = rem / st, tj = rem % st;
  int base = p * 2 * s;
  float acc[4][4] = {};
  gemm64<0, 0>(Am + (size_t)(base + s + ti * 64) * n + base + s, n,
               Tm + (size_t)p * s * s + tj * 64, s, 0, (ti + 1) * 64, acc, sm);
  float* C = Am + (size_t)(base + s + ti * 64) * n + base + tj * 64;
#pragma unroll
  for (int ii = 0; ii < 4; ++ii)
#pragma unroll
    for (int jj = 0; jj < 4; ++jj) C[(size_t)(ty * 4 + ii) * n + tx * 4 + jj] = -acc[ii][jj];
}

// syrk + fused alpha (+= G*(y-c)) + fused tr(G)
__global__ __launch_bounds__(256) void k_syrkAT(const float* __restrict__ yc, float* ws, int n) {
  __shared__ SMem sm;
  int job = blockIdx.x, m = blockIdx.y, tid = threadIdx.x;
  int tx = tid & 15, ty = tid >> 4;
  const float* Am = ws + OFF_A + (size_t)m * 1048576;
  float* Gm = ws + (size_t)m * 1048576;
  const float* ym = yc + (size_t)m * NC;
  float* accp = ws + OFF_ACC + m * 8;
  float* al = ws + OFF_ALPHA + (size_t)m * 1024;
  float cm = ws[OFF_SCAL + m * 32 + 15];
  int ib, jb; lt_decode(job, ib, jb);
  if (tid < 64) sm.ai[tid] = ym[ib * 64 + tid] - cm;
  else if (tid < 128) sm.aj[tid - 64] = ym[jb * 64 + tid - 64] - cm;
  float acc[4][4] = {};
  gemm64<1, 0>(Am + ib * 64, n, Am + jb * 64, n, ib * 64, n, acc, sm);
#pragma unroll
  for (int ii = 0; ii < 4; ++ii)
#pragma unroll
    for (int jj = 0; jj < 4; ++jj) {
      int r = ty * 4 + ii, c = tx * 4 + jj;
      Gm[(size_t)(ib * 64 + r) * n + jb * 64 + c] = acc[ii][jj];
      if (ib != jb) Gm[(size_t)(jb * 64 + c) * n + ib * 64 + r] = acc[ii][jj];
    }
  if (ib == jb && tx == ty) {
    atomicAdd(&accp[2], acc[0][0] + acc[1][1] + acc[2][2] + acc[3][3]);
  }
  float rowp[4];
#pragma unroll
  for (int i = 0; i < 4; ++i) {
    float s = 0.0f;
#pragma unroll
    for (int j = 0; j < 4; ++j) s = fmaf(acc[i][j], sm.aj[tx * 4 + j], s);
    rowp[i] = s;
  }
  float colp[4];
  if (ib != jb) {
#pragma unroll
    for (int j = 0; j < 4; ++j) {
      float s = 0.0f;
#pragma unroll
      for (int i = 0; i < 4; ++i) s = fmaf(acc[i][j], sm.ai[ty * 4 + i], s);
      colp[j] = s;
    }
  }
  __syncthreads();
  float* redA = &sm.As[0][0];
  float* redB = &sm.Bs[0][0];
#pragma unroll
  for (int i = 0; i < 4; ++i) redA[(ty * 4 + i) * 16 + tx] = rowp[i];
  if (ib != jb) {
#pragma unroll
    for (int j = 0; j < 4; ++j) redB[(tx * 4 + j) * 16 + ty] = colp[j];
  }
  __syncthreads();
  if (tid < 64) {
    float s = 0.0f;
#pragma unroll
    for (int q = 0; q < 16; ++q) s += redA[tid * 16 + q];
    atomicAdd(&al[ib * 64 + tid], s);
    if (ib != jb) {
      float s2 = 0.0f;
#pragma unroll
      for (int q = 0; q < 16; ++q) s2 += redB[tid * 16 + q];
      atomicAdd(&al[jb * 64 + tid], s2);
    }
  }
}

// reduce: T1 = <G,C>, T2 = alpha^T C alpha (lower-tri, weight 2 off-diag)
// + ticket: the LAST block to finish runs the Adam update inline.
__global__ __launch_bounds__(256) void k_reduceAD(const float* __restrict__ xc,
                                                  const float* __restrict__ yc,
                                                  float* ws, int n, int tstep) {
  __shared__ SMem sm;
  __shared__ unsigned tkt;
  int job = blockIdx.x, m = blockIdx.y, tid = threadIdx.x;
  const float* xm = xc + (size_t)m * NC * 3;
  const float* Gm = ws + (size_t)m * 1048576;
  const float* al = ws + OFF_ALPHA + (size_t)m * 1024;
  float* accp = ws + OFF_ACC + m * 8;
  float* sT = ws + OFF_SCAL + m * 32;
  int nb = n >> 6;
  int njobs = nb * (nb + 1) / 2;
  float ls = sT[12], os = sT[13];
  float il2 = 1.0f / (ls * ls);
  float c53 = (5.0f / 3.0f) * os / ls;
  int bi, bj; lt_decode(job, bi, bj);
  float w = (bi == bj) ? 1.0f : 2.0f;
  if (tid < 64) {
    int r = bi * 64 + tid;
    sm.xi[tid][0] = xm[r * 3 + 0]; sm.xi[tid][1] = xm[r * 3 + 1]; sm.xi[tid][2] = xm[r * 3 + 2];
    sm.ai[tid] = al[r];
  } else if (tid < 128) {
    int lr = tid - 64; int r = bj * 64 + lr;
    sm.xj[lr][0] = xm[r * 3 + 0]; sm.xj[lr][1] = xm[r * 3 + 1]; sm.xj[lr][2] = xm[r * 3 + 2];
    sm.aj[lr] = al[r];
  }
  __syncthreads();
  float a1 = 0.0f, a2 = 0.0f;
  for (int e = tid; e < 4096; e += 256) {
    int r = e >> 6, c = e & 63;
    float d0 = sm.xi[r][0] - sm.xj[c][0], d1 = sm.xi[r][1] - sm.xj[c][1], d2 = sm.xi[r][2] - sm.xj[c][2];
    float r2 = d0 * d0 + d1 * d1 + d2 * d2;
    float z = fmaxf(r2 * il2, 1e-12f);
    float dd = sqrtf(z);
    float Cv = c53 * z * (1.0f + S5 * dd) * __expf(-S5 * dd);
    float g = Gm[(size_t)(bi * 64 + r) * n + bj * 64 + c];
    a1 = fmaf(g, Cv, a1);
    a2 = fmaf(sm.ai[r] * sm.aj[c], Cv, a2);
  }
  a1 *= w; a2 *= w;
  for (int off = 32; off; off >>= 1) { a1 += __shfl_down(a1, off); a2 += __shfl_down(a2, off); }
  int wid = tid >> 6, lane = tid & 63;
  if (lane == 0) { sm.red[wid][0] = a1; sm.red[wid][1] = a2; }
  __syncthreads();
  if (tid == 0) {
    a1 = sm.red[0][0] + sm.red[1][0] + sm.red[2][0] + sm.red[3][0];
    a2 = sm.red[0][1] + sm.red[1][1] + sm.red[2][1] + sm.red[3][1];
    atomicAdd(&accp[0], a1);
    atomicAdd(&accp[1], a2);
  }
  // completion ticket; last block runs Adam inline
  __threadfence();
  if (tid == 0)
    tkt = __hip_atomic_fetch_add((unsigned*)(ws + OFF_CTR) + m, 1u,
                                 __ATOMIC_ACQ_REL, __HIP_MEMORY_SCOPE_AGENT);
  __syncthreads();
  if (tkt != (unsigned)(njobs - 1)) return;
  const float* ym = yc + (size_t)m * NC;
  float cm = sT[15];
  float t4 = 0, t5 = 0, t6 = 0;
  for (int i = tid; i < n; i += 256) {
    float a = al[i];
    t4 = fmaf(a, a, t4); t5 += a; t6 = fmaf(ym[i] - cm, a, t6);
  }
  for (int off = 32; off; off >>= 1) {
    t4 += __shfl_down(t4, off); t5 += __shfl_down(t5, off); t6 += __shfl_down(t6, off);
  }
  __syncthreads();
  if (lane == 0) { sm.red[wid][0] = t4; sm.red[wid][1] = t5; sm.red[wid][2] = t6; }
  __syncthreads();
  if (tid == 0) {
    t4 = sm.red[0][0] + sm.red[1][0] + sm.red[2][0] + sm.red[3][0];
    t5 = sm.red[0][1] + sm.red[1][1] + sm.red[2][1] + sm.red[3][1];
    t6 = sm.red[0][2] + sm.red[1][2] + sm.red[2][2] + sm.red[3][2];
    float T1 = __hip_atomic_fetch_add(&accp[0], 0.0f, __ATOMIC_RELAXED, __HIP_MEMORY_SCOPE_AGENT);
    float T2 = __hip_atomic_fetch_add(&accp[1], 0.0f, __ATOMIC_RELAXED, __HIP_MEMORY_SCOPE_AGENT);
    float t3 = __hip_atomic_fetch_add(&accp[2], 0.0f, __ATOMIC_RELAXED, __HIP_MEMORY_SCOPE_AGENT);
    float noi = sT[14];
    float fn = (float)n;
    float g_ls = 0.5f / fn * (T1 - T2);
    float g_os = 0.5f / (fn * os) * (fn - noi * t3 - t6 + noi * t4);
    float g_no = 0.5f / fn * (t3 - t4);
    float g_c = -t5 / fn;
    float gr[4];
    gr[0] = g_ls * sigmf(sT[0]);
    gr[1] = g_os * sigmf(sT[1]);
    gr[2] = g_no * sigmf(sT[2]);
    gr[3] = g_c;
    float bc1 = 1.0f - powf(0.9f, (float)tstep);
    float bc2 = 1.0f - powf(0.999f, (float)tstep);
#pragma unroll
    for (int i = 0; i < 4; ++i) {
      float mv = 0.9f * sT[4 + i] + 0.1f * gr[i];
      float vv = 0.999f * sT[8 + i] + 0.001f * gr[i] * gr[i];
      sT[4 + i] = mv; sT[8 + i] = vv;
      sT[i] = sT[i] - 0.1f * (mv / bc1) / (sqrtf(vv / bc2) + 1e-8f);
    }
    sT[12] = softplusf(sT[0]);
    sT[13] = softplusf(sT[1]);
    sT[14] = softplusf(sT[2]) + 1e-4f;
    sT[15] = sT[3];
  }
}

// prediction
__global__ __launch_bounds__(256) void k_buildKtc(const float* __restrict__ xt,
                                                  const float* __restrict__ xc, float* ws) {
  __shared__ SMem sm;
  int job = blockIdx.x, m = blockIdx.y, tid = threadIdx.x;
  const float* xtm = xt + (size_t)m * NT * 3;
  const float* xm = xc + (size_t)m * NC * 3;
  float* Kt = ws + OFF_KTC + (size_t)m * NT * NC;
  float* Tm = ws + OFF_T + (size_t)m * 262144;  // S1 at Tm, S2 at Tm+NT
  const float* sT = ws + OFF_SCAL + m * 32;
  float ls = sT[12], os = sT[13];
  float il2 = 1.0f / (ls * ls);
  if (job < 2) {
    int z = job * 256 + tid;
    Tm[z] = 0.0f; Tm[NT + z] = 0.0f;
  }
  int ti = job >> 4, tj = job & 15;
  if (tid < 64) {
    int r = ti * 64 + tid;
    sm.xi[tid][0] = xtm[r * 3 + 0]; sm.xi[tid][1] = xtm[r * 3 + 1]; sm.xi[tid][2] = xtm[r * 3 + 2];
  } else if (tid < 128) {
    int lr = tid - 64; int r = tj * 64 + lr;
    sm.xj[lr][0] = xm[r * 3 + 0]; sm.xj[lr][1] = xm[r * 3 + 1]; sm.xj[lr][2] = xm[r * 3 + 2];
  }
  __syncthreads();
  for (int e = tid; e < 4096; e += 256) {
    int r = e >> 6, c = e & 63;
    float d0 = sm.xi[r][0] - sm.xj[c][0], d1 = sm.xi[r][1] - sm.xj[c][1], d2 = sm.xi[r][2] - sm.xj[c][2];
    float r2 = d0 * d0 + d1 * d1 + d2 * d2;
    float z = fmaxf(r2 * il2, 1e-12f);
    float dd = sqrtf(z);
    float kv = os * (1.0f + S5 * dd + (5.0f / 3.0f) * z) * __expf(-S5 * dd);
    Kt[(size_t)(ti * 64 + r) * NC + tj * 64 + c] = kv;
  }
}

// W-tile = Ktc*G in-register; fused S1 += Ktc.alpha, S2 += Ktc.W
__global__ __launch_bounds__(256) void k_predW(float* ws) {
  __shared__ SMem sm;
  int job = blockIdx.x, m = blockIdx.y, tid = threadIdx.x;
  int tx = tid & 15, ty = tid >> 4;
  const float* Kt = ws + OFF_KTC + (size_t)m * NT * NC;
  const float* Gm = ws + (size_t)m * 1048576;
  const float* al = ws + OFF_ALPHA + (size_t)m * 1024;
  float* S1 = ws + OFF_T + (size_t)m * 262144;
  float* S2 = S1 + NT;
  int ti = job >> 4, tj = job & 15;
  if (tid < 64) sm.aj[tid] = al[tj * 64 + tid];
  float acc[4][4] = {};
  gemm64<0, 0>(Kt + (size_t)(ti * 64) * NC, NC, Gm + tj * 64, 1024, 0, 1024, acc, sm);
  float s1p[4], s2p[4];
#pragma unroll
  for (int i = 0; i < 4; ++i) {
    float a1 = 0.0f, a2 = 0.0f;
    const float* kr = Kt + (size_t)(ti * 64 + ty * 4 + i) * NC + tj * 64;
#pragma unroll
    for (int j = 0; j < 4; ++j) {
      float kv = kr[tx * 4 + j];
      a1 = fmaf(kv, sm.aj[tx * 4 + j], a1);
      a2 = fmaf(kv, acc[i][j], a2);
    }
    s1p[i] = a1; s2p[i] = a2;
  }
  __syncthreads();
  float* redA = &sm.As[0][0];
  float* redB = &sm.Bs[0][0];
#pragma unroll
  for (int i = 0; i < 4; ++i) {
    redA[(ty * 4 + i) * 16 + tx] = s1p[i];
    redB[(ty * 4 + i) * 16 + tx] = s2p[i];
  }
  __syncthreads();
  if (tid < 64) {
    float a1 = 0.0f, a2 = 0.0f;
#pragma unroll
    for (int q = 0; q < 16; ++q) { a1 += redA[tid * 16 + q]; a2 += redB[tid * 16 + q]; }
    atomicAdd(&S1[ti * 64 + tid], a1);
    atomicAdd(&S2[ti * 64 + tid], a2);
  }
}

__global__ __launch_bounds__(256) void k_final(float* ws, float* out) {
  int m = blockIdx.y, t = blockIdx.x * 256 + threadIdx.x;
  const float* S1 = ws + OFF_T + (size_t)m * 262144;
  const float* S2 = S1 + NT;
  const float* sT = ws + OFF_SCAL + m * 32;
  if (t < NT) {
    out[(size_t)m * NT + t] = sT[15] + S1[t];
    out[(size_t)MM * NT + (size_t)m * NT + t] = sT[13] + sT[14] - S2[t];
  }
}

// ---------------- host: discrete graph pipeline ------------------------------
extern "C" void kernel_launch(void* const* d_in, const int* in_sizes, int n_in,
                              void* d_out, int out_size, void* d_ws, size_t ws_size,
                              hipStream_t stream) {
  const float* xc = (const float*)d_in[0];
  const float* yc = (const float*)d_in[1];
  const float* xt = (const float*)d_in[2];
  float* out = (float*)d_out;
  float* ws = (float*)d_ws;

  k_init<<<dim3(1), dim3(256), 0, stream>>>(ws);

  for (int step = 0; step < 17; ++step) {
    int n = step < 8 ? 512 : 1024;
    int nb = n >> 6;
    k_buildK<<<dim3(nb * (nb + 1) / 2, MM), dim3(256), 0, stream>>>(xc, ws, n);
    for (int k = 0; k <= nb - 2; ++k) {
      int t = nb - 1 - k;
      k_trail<<<dim3(t * (t + 1) / 2, MM), dim3(256), 0, stream>>>(ws, k, n);
    }
    k_trinv64<<<dim3(n / 128, MM), dim3(256), 0, stream>>>(ws, n);
    for (int s = 128; s < n; s <<= 1) {
      int st = s >> 6, np = n / (2 * s);
      k_trinvT<<<dim3(np * st * st, MM), dim3(256), 0, stream>>>(ws, s, n);
      k_trinvA<<<dim3(np * st * st, MM), dim3(256), 0, stream>>>(ws, s, n);
    }
    k_syrkAT<<<dim3(nb * (nb + 1) / 2, MM), dim3(256), 0, stream>>>(yc, ws, n);
    if (step < 16) {
      k_reduceAD<<<dim3(nb * (nb + 1) / 2, MM), dim3(256), 0, stream>>>(xc, yc, ws, n, step + 1);
    }
  }

  k_buildKtc<<<dim3(128, MM), dim3(256), 0, stream>>>(xt, xc, ws);
  k_predW<<<dim3(128, MM), dim3(256), 0, stream>>>(ws);
  k_final<<<dim3(2, MM), dim3(256), 0, stream>>>(ws, out);

  (void)in_sizes; (void)n_in; (void)out_size; (void)ws_size;
}